// Round 17
// baseline (243.957 us; speedup 1.0000x reference)
//
#include <hip/hip_runtime.h>
#include <hip/hip_bf16.h>
#include <math.h>

#define NBATCH 512
#define TT 64
#define EMB 512
#define NHEADS 8
#define HDIM 64
#define MROWS (NBATCH * TT)          // 32768
#define ROWSTRIDE (TT * EMB)         // 32768 elems per batch row of a plane
#define WSEG 262144                  // 512*512 weight elems

// 1/sqrt(512) * log2(e): folded into Wq/bq so attn logits are in log2 domain
static constexpr float QSCALE = 0.0637587140f;

typedef __attribute__((ext_vector_type(8))) short short8v;  // 8 bf16 (4 VGPR)
typedef __attribute__((ext_vector_type(4))) float f32x4;

__device__ __forceinline__ unsigned short f2bf(float x) {
    union { float f; unsigned int u; } v; v.f = x;
    unsigned int r = v.u + 0x7fff + ((v.u >> 16) & 1);   // RNE
    return (unsigned short)(r >> 16);
}

// v_cvt_pk_bf16_f32: packs lo->bits[15:0], hi->bits[31:16], RNE
__device__ __forceinline__ unsigned int cvtpk(float lo, float hi) {
    unsigned int r;
    asm("v_cvt_pk_bf16_f32 %0, %1, %2" : "=v"(r) : "v"(lo), "v"(hi));
    return r;
}

__device__ __forceinline__ void gl16(const void* g, void* l) {
    __builtin_amdgcn_global_load_lds(
        (const __attribute__((address_space(1))) unsigned int*)g,
        (__attribute__((address_space(3))) unsigned int*)l, 16, 0, 0);
}

// ---------------------------------------------------------------------------
// inputs fp32 -> bf16 (3 planes, 288 MB traffic, at BW floor ~45 us)
// ---------------------------------------------------------------------------
__global__ __launch_bounds__(256) void cvt3(
    const float* __restrict__ a, const float* __restrict__ b, const float* __restrict__ c,
    unsigned short* __restrict__ oa, unsigned short* __restrict__ ob, unsigned short* __restrict__ oc)
{
    const size_t i = (size_t)blockIdx.x * 256 + threadIdx.x;   // x4 elems
    float4 va = reinterpret_cast<const float4*>(a)[i];
    float4 vb = reinterpret_cast<const float4*>(b)[i];
    float4 vc = reinterpret_cast<const float4*>(c)[i];
    ushort4 ra, rb, rc;
    ra.x = f2bf(va.x); ra.y = f2bf(va.y); ra.z = f2bf(va.z); ra.w = f2bf(va.w);
    rb.x = f2bf(vb.x); rb.y = f2bf(vb.y); rb.z = f2bf(vb.z); rb.w = f2bf(vb.w);
    rc.x = f2bf(vc.x); rc.y = f2bf(vc.y); rc.z = f2bf(vc.z); rc.w = f2bf(vc.w);
    reinterpret_cast<ushort4*>(oa)[i] = ra;
    reinterpret_cast<ushort4*>(ob)[i] = rb;
    reinterpret_cast<ushort4*>(oc)[i] = rc;
}

// ---------------------------------------------------------------------------
// weights fp32 -> bf16 (4 MB); seg 0 (Wq) pre-scaled by QSCALE
// ---------------------------------------------------------------------------
__global__ __launch_bounds__(256) void cvtw(
    const float* __restrict__ w0, const float* __restrict__ w1,
    const float* __restrict__ w2, const float* __restrict__ w3,
    unsigned short* __restrict__ dst)
{
    const int seg = blockIdx.y;
    const float* src = (seg == 0) ? w0 : (seg == 1) ? w1 : (seg == 2) ? w2 : w3;
    const float sc = (seg == 0) ? QSCALE : 1.0f;
    const size_t i = (size_t)blockIdx.x * 256 + threadIdx.x;   // x4 elems
    float4 v = reinterpret_cast<const float4*>(src)[i];
    ushort4 r;
    r.x = f2bf(v.x * sc); r.y = f2bf(v.y * sc); r.z = f2bf(v.z * sc); r.w = f2bf(v.w * sc);
    reinterpret_cast<ushort4*>(dst + (size_t)seg * WSEG)[i] = r;
}

// ---------------------------------------------------------------------------
// Merged q/k/v projection GEMMs: 256x256 tile, BK=64, deep-MFMA counted-vmcnt
// pipeline (r16-verified sync skeleton + 4x the MFMA per barrier-pair):
//   prologue: issue K-tiles 0,1 (8 gl16/thread each)
//   iter t:  s_waitcnt vmcnt(8)  <- tile t done, t+1 stays in flight
//            s_barrier
//            setprio(1); 128 MFMA/wave from buf[t&1]; setprio(0)
//            s_waitcnt lgkmcnt(0); s_barrier
//            issue tile t+2 into buf[t&1]
// 512 thr / 8 waves (2M x 4N); per-wave 128x64 out, acc[8][4].
// A and W both staged bf16 via gl16 with the session-verified 16B-unit XOR
// swizzle phys_u = u ^ (row&7) (source-preswizzled + matching XOR on read).
// LDS 2 x (32+32) KB = 128 KB -> 1 block/CU; the counted vmcnt keeps loads
// flowing across barriers (the m201 mechanism).
// ---------------------------------------------------------------------------
__global__ __launch_bounds__(512, 2) void gemm_proj3(
    const unsigned short* __restrict__ A0, const unsigned short* __restrict__ A1,
    const unsigned short* __restrict__ A2, const unsigned short* __restrict__ Wb,
    const float* __restrict__ b0, const float* __restrict__ b1, const float* __restrict__ b2,
    unsigned short* __restrict__ o0, unsigned short* __restrict__ o1, unsigned short* __restrict__ o2)
{
    __shared__ __align__(16) unsigned short Asb[2][256 * 64];  // 2 x 32 KB
    __shared__ __align__(16) unsigned short Bsb[2][256 * 64];  // 2 x 32 KB
    const int z = blockIdx.z;
    const unsigned short* A = (z == 0) ? A0 : (z == 1) ? A1 : A2;
    const unsigned short* W = Wb + (size_t)z * WSEG;
    const float* bias = (z == 0) ? b0 : (z == 1) ? b1 : b2;
    const float bsc = (z == 0) ? QSCALE : 1.0f;
    unsigned short* Cout = (z == 0) ? o0 : (z == 1) ? o1 : o2;

    const int tid = threadIdx.x;
    const int wave = tid >> 6, lane = tid & 63;
    const int lg = lane >> 4, li = lane & 15;
    const int m0 = blockIdx.x * 256;
    const int n0 = blockIdx.y * 256;
    const int wm = (wave >> 2) * 128;       // wave row offset (0/128)
    const int wn = (wave & 3) * 64;         // wave col offset (0..192)

    f32x4 acc[8][4] = {};

    // Staging: per instr i (0..3), thread t covers row (t>>3)+i*64, phys
    // 16B-unit t&7; source supplies logical unit (t&7)^(row&7); row&7 is
    // i-invariant ((t>>3)&7). LDS offset = t*8 + i*4096 (linear in t ✓).
    const int au = (tid & 7) ^ ((tid >> 3) & 7);
    const unsigned short* gA = A + (size_t)(m0 + (tid >> 3)) * 512 + au * 8;
    const unsigned short* gW = W + (size_t)(n0 + (tid >> 3)) * 512 + au * 8;

#define ISSUE(t, bb) do {                                                   \
        const int _k0 = (t) * 64;                                           \
        _Pragma("unroll")                                                   \
        for (int _i = 0; _i < 4; _i++) {                                    \
            gl16(gA + _k0 + (size_t)_i * 64 * 512,                          \
                 &Asb[bb][wave * 512 + _i * 4096]);                         \
            gl16(gW + _k0 + (size_t)_i * 64 * 512,                          \
                 &Bsb[bb][wave * 512 + _i * 4096]);                         \
        }                                                                   \
    } while (0)

    ISSUE(0, 0);
    ISSUE(1, 1);

    for (int t = 0; t < 8; ++t) {
        if (t < 7) { asm volatile("s_waitcnt vmcnt(8)" ::: "memory"); }
        else       { asm volatile("s_waitcnt vmcnt(0)" ::: "memory"); }
        __builtin_amdgcn_s_barrier();
        __builtin_amdgcn_sched_barrier(0);

        const int b = t & 1;
        __builtin_amdgcn_s_setprio(1);
#pragma unroll
        for (int kf = 0; kf < 2; kf++) {
            const int xofs = (kf * 32 + lg * 8);
            short8v bfr[4];
#pragma unroll
            for (int nf = 0; nf < 4; nf++) {
                const int rB = wn + nf * 16 + li;
                bfr[nf] = *reinterpret_cast<const short8v*>(
                    &Bsb[b][rB * 64 + (xofs ^ ((rB & 7) * 8))]);
            }
#pragma unroll
            for (int mf = 0; mf < 8; mf++) {
                const int rA = wm + mf * 16 + li;
                const short8v af = *reinterpret_cast<const short8v*>(
                    &Asb[b][rA * 64 + (xofs ^ ((rA & 7) * 8))]);
#pragma unroll
                for (int nf = 0; nf < 4; nf++)
                    acc[mf][nf] = __builtin_amdgcn_mfma_f32_16x16x32_bf16(af, bfr[nf], acc[mf][nf], 0, 0, 0);
            }
        }
        __builtin_amdgcn_s_setprio(0);

        asm volatile("s_waitcnt lgkmcnt(0)" ::: "memory");
        __builtin_amdgcn_s_barrier();
        __builtin_amdgcn_sched_barrier(0);
        if (t + 2 < 8) ISSUE(t + 2, b);
    }
#undef ISSUE

    // epilogue: row = m0+wm+mf*16+lg*4+r, col = n0+wn+nf*16+li
#pragma unroll
    for (int nf = 0; nf < 4; nf++) {
        const int col = n0 + wn + nf * 16 + li;
        const float bb = bias[col] * bsc;
#pragma unroll
        for (int mf = 0; mf < 8; mf++) {
            const int row0 = m0 + wm + mf * 16 + lg * 4;
#pragma unroll
            for (int r = 0; r < 4; r++)
                Cout[(size_t)(row0 + r) * 512 + col] = f2bf(acc[mf][nf][r] + bb);
        }
    }
}

// ---------------------------------------------------------------------------
// bf16 GEMM, f32 output (Wo projection). m97 structure, BK=32, grid (256,4).
// At its BW floor (~31 us) — unchanged.
// ---------------------------------------------------------------------------
__global__ __launch_bounds__(256) void gemm_out(
    const unsigned short* __restrict__ A, const unsigned short* __restrict__ W,
    const float* __restrict__ bias, float* __restrict__ Cout)
{
    __shared__ __align__(16) unsigned short As[128 * 32];
    __shared__ __align__(16) unsigned short Bs[128 * 32];
    const int tid = threadIdx.x;
    const int wave = tid >> 6, lane = tid & 63;
    const int lg = lane >> 4, li = lane & 15;
    const int m0 = blockIdx.x * 128;
    const int n0 = blockIdx.y * 128;
    const int wr = (wave >> 1) * 64;
    const int wc = (wave & 1) * 64;

    f32x4 acc[4][4] = {};

    const unsigned short* ga = A + (size_t)(m0 + (tid >> 2)) * 512 + (tid & 3) * 8;
    const unsigned short* gb = W + (size_t)(n0 + (tid >> 2)) * 512 + (tid & 3) * 8;
    unsigned short* lA = &As[wave * 512];
    unsigned short* lB = &Bs[wave * 512];

    for (int k0 = 0; k0 < 512; k0 += 32) {
        __syncthreads();
        gl16(ga + k0, lA);
        gl16(ga + k0 + 64 * 512, lA + 2048);
        gl16(gb + k0, lB);
        gl16(gb + k0 + 64 * 512, lB + 2048);
        __syncthreads();

        short8v af[4], bfr[4];
#pragma unroll
        for (int i = 0; i < 4; i++) {
            af[i]  = *reinterpret_cast<const short8v*>(&As[(wr + i * 16 + li) * 32 + lg * 8]);
            bfr[i] = *reinterpret_cast<const short8v*>(&Bs[(wc + i * 16 + li) * 32 + lg * 8]);
        }
#pragma unroll
        for (int i = 0; i < 4; i++)
#pragma unroll
            for (int j = 0; j < 4; j++)
                acc[i][j] = __builtin_amdgcn_mfma_f32_16x16x32_bf16(af[i], bfr[j], acc[i][j], 0, 0, 0);
    }

#pragma unroll
    for (int j = 0; j < 4; j++) {
        const int col = n0 + wc + j * 16 + li;
        const float bb = bias[col];
#pragma unroll
        for (int i = 0; i < 4; i++) {
            const int row0 = m0 + wr + i * 16 + lg * 4;
#pragma unroll
            for (int r = 0; r < 4; r++)
                Cout[(size_t)(row0 + r) * 512 + col] = acc[i][j][r] + bb;
        }
    }
}

// ---------------------------------------------------------------------------
// bf16 flash attention v4 (round-14 verified, unchanged). QBLK=256,
// grid = (2, 512), 256 thr / 4 waves, wave owns 64 q-rows.
// ---------------------------------------------------------------------------
__global__ __launch_bounds__(256) void attn_bf16(
    const unsigned short* __restrict__ qp, const unsigned short* __restrict__ kp,
    const unsigned short* __restrict__ vp, unsigned short* __restrict__ ao)
{
    __shared__ __align__(16) unsigned short Ks[64 * 64];    // XOR-swizzled rows
    __shared__ __align__(16) unsigned short Vt[64][68];     // [d][key], pad 68
    __shared__ __align__(16) unsigned short Pl[4][16][72];  // per-wave P chunk

    const int tid = threadIdx.x;
    const int wave = tid >> 6, lane = tid & 63;
    const int lg = lane >> 4, li = lane & 15;
    const int n0 = blockIdx.x * 256;
    const int th = blockIdx.y;
    const size_t base = (size_t)(th >> 3) * EMB + (size_t)(th & 7) * HDIM;

    // ---- Q frags direct from global (one-time scatter; qb is L2/L3-warm) ----
    short8v qf[4][2];
#pragma unroll
    for (int mf = 0; mf < 4; mf++)
#pragma unroll
        for (int kf = 0; kf < 2; kf++)
            qf[mf][kf] = *reinterpret_cast<const short8v*>(
                qp + (size_t)(n0 + wave * 64 + mf * 16 + li) * ROWSTRIDE
                   + base + kf * 32 + lg * 8);

    // ---- V prefetch (tile 0): 4x4 micro-tile, 4 x global b64 ----
    const int vd0 = (tid & 15) * 4;
    const int vk0 = (tid >> 4) * 4;
    const unsigned short* gv = vp + base + vd0;
    uint2 vl[4];
#pragma unroll
    for (int i = 0; i < 4; i++)
        vl[i] = *reinterpret_cast<const uint2*>(gv + (size_t)(vk0 + i) * ROWSTRIDE);

    const short8v ones = (short8v)(short)0x3F80;   // bf16 1.0 splat
    f32x4 acc[4][4] = {};
    f32x4 acc_l[4] = {};

    for (int kv = 0; kv < 8; kv++) {
        const int k0 = kv * 64;
        __syncthreads();   // prior tile reads complete

        // stage K (XOR-swizzled source) — verified pattern
        {
            unsigned short* lk = &Ks[wave * 512];
#pragma unroll
            for (int i = 0; i < 2; i++) {
                const int r = (tid >> 3) + i * 32;
                const int srcofs = (((tid & 7) * 8) ^ ((r & 7) * 8));
                gl16(kp + (size_t)(k0 + r) * ROWSTRIDE + base + srcofs, lk + i * 2048);
            }
        }
        // stage V^T: in-reg 4x4 micro-tile transpose — verified pattern
#pragma unroll
        for (int dd = 0; dd < 4; dd++) {
            const unsigned int sel = (dd & 1) ? 0x07060302u : 0x05040100u;
            const unsigned int a = (dd < 2) ? vl[0].x : vl[0].y;
            const unsigned int b = (dd < 2) ? vl[1].x : vl[1].y;
            const unsigned int c = (dd < 2) ? vl[2].x : vl[2].y;
            const unsigned int d = (dd < 2) ? vl[3].x : vl[3].y;
            uint2 o;
            o.x = __builtin_amdgcn_perm(b, a, sel);
            o.y = __builtin_amdgcn_perm(d, c, sel);
            *reinterpret_cast<uint2*>(&Vt[vd0 + dd][vk0]) = o;
        }
        __syncthreads();   // K (vmcnt) drained, Vt visible

        // prefetch next V tile under compute
        if (kv < 7) {
#pragma unroll
            for (int i = 0; i < 4; i++)
                vl[i] = *reinterpret_cast<const uint2*>(
                    gv + (size_t)(k0 + 64 + vk0 + i) * ROWSTRIDE);
        }

        // hoist K and V frags to regs (read LDS once per iter)
        short8v kfr[4][2], vfr[4][2];
#pragma unroll
        for (int nf = 0; nf < 4; nf++) {
            const int key = nf * 16 + li;
#pragma unroll
            for (int kf = 0; kf < 2; kf++)
                kfr[nf][kf] = *reinterpret_cast<const short8v*>(
                    &Ks[key * 64 + ((kf * 32 + lg * 8) ^ ((key & 7) * 8))]);
        }
#pragma unroll
        for (int df = 0; df < 4; df++)
#pragma unroll
            for (int kf = 0; kf < 2; kf++)
                vfr[df][kf] = *reinterpret_cast<const short8v*>(
                    &Vt[df * 16 + li][kf * 32 + lg * 8]);

        // ---- per-mf: QK^T -> softmax -> P chunk -> l-sum + PV ----
#pragma unroll
        for (int mf = 0; mf < 4; mf++) {
            f32x4 s[4] = {};
#pragma unroll
            for (int nf = 0; nf < 4; nf++)
#pragma unroll
                for (int kf = 0; kf < 2; kf++)
                    s[nf] = __builtin_amdgcn_mfma_f32_16x16x32_bf16(kfr[nf][kf], qf[mf][kf], s[nf], 0, 0, 0);

#pragma unroll
            for (int nf = 0; nf < 4; nf++) {
                const float p0 = exp2f(s[nf][0]);
                const float p1 = exp2f(s[nf][1]);
                const float p2 = exp2f(s[nf][2]);
                const float p3 = exp2f(s[nf][3]);
                union { unsigned int u[2]; uint2 v; } pk2;
                pk2.u[0] = cvtpk(p0, p1);
                pk2.u[1] = cvtpk(p2, p3);
                *reinterpret_cast<uint2*>(&Pl[wave][li][nf * 16 + lg * 4]) = pk2.v;
            }

            short8v pf[2];
#pragma unroll
            for (int kf = 0; kf < 2; kf++)
                pf[kf] = *reinterpret_cast<const short8v*>(
                    &Pl[wave][li][kf * 32 + lg * 8]);
#pragma unroll
            for (int kf = 0; kf < 2; kf++)
                acc_l[mf] = __builtin_amdgcn_mfma_f32_16x16x32_bf16(pf[kf], ones, acc_l[mf], 0, 0, 0);
#pragma unroll
            for (int df = 0; df < 4; df++)
#pragma unroll
                for (int kf = 0; kf < 2; kf++)
                    acc[mf][df] = __builtin_amdgcn_mfma_f32_16x16x32_bf16(pf[kf], vfr[df][kf], acc[mf][df], 0, 0, 0);
        }
    }

    // ---- epilogue: divide by l, store bf16 ----
#pragma unroll
    for (int mf = 0; mf < 4; mf++) {
#pragma unroll
        for (int r = 0; r < 4; r++) {
            const float linv = 1.0f / acc_l[mf][r];
            const int qrow = n0 + wave * 64 + mf * 16 + lg * 4 + r;
#pragma unroll
            for (int df = 0; df < 4; df++)
                ao[(size_t)qrow * ROWSTRIDE + base + df * 16 + li] = f2bf(acc[mf][df][r] * linv);
        }
    }
}

extern "C" void kernel_launch(void* const* d_in, const int* in_sizes, int n_in,
                              void* d_out, int out_size, void* d_ws, size_t ws_size,
                              hipStream_t stream) {
    const float* values = (const float*)d_in[0];
    const float* keys   = (const float*)d_in[1];
    const float* query  = (const float*)d_in[2];
    const float* Wv = (const float*)d_in[3];
    const float* bv = (const float*)d_in[4];
    const float* Wk = (const float*)d_in[5];
    const float* bk = (const float*)d_in[6];
    const float* Wq = (const float*)d_in[7];
    const float* bq = (const float*)d_in[8];
    const float* Wo = (const float*)d_in[9];
    const float* bo = (const float*)d_in[10];
    float* out = (float*)d_out;

    unsigned short* ws16 = (unsigned short*)d_ws;
    const size_t PLANE = (size_t)MROWS * EMB;
    unsigned short* xq = ws16;                  // bf16 input copies
    unsigned short* xk = ws16 + PLANE;
    unsigned short* xv = ws16 + 2 * PLANE;
    unsigned short* qb = ws16 + 3 * PLANE;      // projected q/k/v
    unsigned short* kb = ws16 + 4 * PLANE;
    unsigned short* vb = ws16 + 5 * PLANE;
    unsigned short* ab = ws16 + 6 * PLANE;      // attention output
    unsigned short* wb = ws16 + 7 * PLANE;      // 4 bf16 weight mats

    cvt3<<<PLANE / 4 / 256, 256, 0, stream>>>(query, keys, values, xq, xk, xv);
    cvtw<<<dim3(WSEG / 4 / 256, 4), 256, 0, stream>>>(Wq, Wk, Wv, Wo, wb);

    gemm_proj3<<<dim3(MROWS / 256, EMB / 256, 3), 512, 0, stream>>>(
        xq, xk, xv, wb, bq, bk, bv, qb, kb, vb);

    attn_bf16<<<dim3(2, TT * NHEADS), 256, 0, stream>>>(qb, kb, vb, ab);

    gemm_out<<<dim3(MROWS / 128, EMB / 128), 256, 0, stream>>>(
        ab, wb + 3 * WSEG, bo, out);
}

// Round 18
// 220.618 us; speedup vs baseline: 1.1058x; 1.1058x over previous
//
#include <hip/hip_runtime.h>
#include <hip/hip_bf16.h>
#include <math.h>

#define NBATCH 512
#define TT 64
#define EMB 512
#define NHEADS 8
#define HDIM 64
#define MROWS (NBATCH * TT)          // 32768
#define ROWSTRIDE (TT * EMB)         // 32768 elems per batch row of a plane
#define WSEG 262144                  // 512*512 weight elems

// 1/sqrt(512) * log2(e): folded into Wq/bq so attn logits are in log2 domain
static constexpr float QSCALE = 0.0637587140f;

typedef __attribute__((ext_vector_type(8))) short short8v;  // 8 bf16 (4 VGPR)
typedef __attribute__((ext_vector_type(4))) float f32x4;

__device__ __forceinline__ unsigned short f2bf(float x) {
    union { float f; unsigned int u; } v; v.f = x;
    unsigned int r = v.u + 0x7fff + ((v.u >> 16) & 1);   // RNE
    return (unsigned short)(r >> 16);
}

// v_cvt_pk_bf16_f32: packs lo->bits[15:0], hi->bits[31:16], RNE
__device__ __forceinline__ unsigned int cvtpk(float lo, float hi) {
    unsigned int r;
    asm("v_cvt_pk_bf16_f32 %0, %1, %2" : "=v"(r) : "v"(lo), "v"(hi));
    return r;
}

__device__ __forceinline__ void gl16(const void* g, void* l) {
    __builtin_amdgcn_global_load_lds(
        (const __attribute__((address_space(1))) unsigned int*)g,
        (__attribute__((address_space(3))) unsigned int*)l, 16, 0, 0);
}

// ---------------------------------------------------------------------------
// weights fp32 -> bf16 (4 MB); seg 0 (Wq) pre-scaled by QSCALE
// ---------------------------------------------------------------------------
__global__ __launch_bounds__(256) void cvtw(
    const float* __restrict__ w0, const float* __restrict__ w1,
    const float* __restrict__ w2, const float* __restrict__ w3,
    unsigned short* __restrict__ dst)
{
    const int seg = blockIdx.y;
    const float* src = (seg == 0) ? w0 : (seg == 1) ? w1 : (seg == 2) ? w2 : w3;
    const float sc = (seg == 0) ? QSCALE : 1.0f;
    const size_t i = (size_t)blockIdx.x * 256 + threadIdx.x;   // x4 elems
    float4 v = reinterpret_cast<const float4*>(src)[i];
    ushort4 r;
    r.x = f2bf(v.x * sc); r.y = f2bf(v.y * sc); r.z = f2bf(v.z * sc); r.w = f2bf(v.w * sc);
    reinterpret_cast<ushort4*>(dst + (size_t)seg * WSEG)[i] = r;
}

// ---------------------------------------------------------------------------
// Merged q/k/v projection GEMMs: 256x256 tile, BK=64, deep-MFMA counted-vmcnt
// pipeline (round-17 verified skeleton) + FUSED f32->bf16 A conversion:
//   A tile t: f32 loaded to regs one iter ahead (LOADA, issued before ISSUEW
//   so W stays FIFO-oldest), converted with cvtpk and ds_write_b128'd into
//   buf[(t)&1] during the issue slot after the second barrier (T14).
//   W tile: gl16 as in r17. No cvt3 pass; q/k/v read once as f32.
// vmcnt ledger (8 A-ldg + 4 W-gl16 per tile):
//   entry t<7: outstanding [W(t)4, A(t+1)8, W(t+1)4]=16 -> vmcnt(12) = W(t) done
//   post-compute t+1<8: outstanding 12 -> vmcnt(4) = A(t+1) regs done
//   (compiler auto-waits on rA reads backstop any VMEM reordering)
// 512 thr / 8 waves (2M x 4N); per-wave 128x64 out, acc[8][4], 128 MFMA/pair.
// Layout identical to r17: phys 16B-unit u holds logical u^(row&7); XOR on
// read (0 bank conflicts measured in r17).
// ---------------------------------------------------------------------------
__global__ __launch_bounds__(512) void gemm_proj3(
    const float* __restrict__ A0, const float* __restrict__ A1,
    const float* __restrict__ A2, const unsigned short* __restrict__ Wb,
    const float* __restrict__ b0, const float* __restrict__ b1, const float* __restrict__ b2,
    unsigned short* __restrict__ o0, unsigned short* __restrict__ o1, unsigned short* __restrict__ o2)
{
    __shared__ __align__(16) unsigned short Asb[2][256 * 64];  // 2 x 32 KB
    __shared__ __align__(16) unsigned short Bsb[2][256 * 64];  // 2 x 32 KB
    const int z = blockIdx.z;
    const float* A = (z == 0) ? A0 : (z == 1) ? A1 : A2;
    const unsigned short* W = Wb + (size_t)z * WSEG;
    const float* bias = (z == 0) ? b0 : (z == 1) ? b1 : b2;
    const float bsc = (z == 0) ? QSCALE : 1.0f;
    unsigned short* Cout = (z == 0) ? o0 : (z == 1) ? o1 : o2;

    const int tid = threadIdx.x;
    const int wave = tid >> 6, lane = tid & 63;
    const int lg = lane >> 4, li = lane & 15;
    const int m0 = blockIdx.x * 256;
    const int n0 = blockIdx.y * 256;
    const int wm = (wave >> 2) * 128;       // wave row offset (0/128)
    const int wn = (wave & 3) * 64;         // wave col offset (0..192)

    f32x4 acc[8][4] = {};

    // W staging (gl16, source-preswizzled): instr i covers row (t>>3)+i*64,
    // phys unit t&7 holds logical (t&7)^(row&7).
    const int au = (tid & 7) ^ ((tid >> 3) & 7);
    const unsigned short* gW = W + (size_t)(n0 + (tid >> 3)) * 512 + au * 8;
    // A f32: thread covers rows (t>>3)+i*64, logical unit t&7 (f32 elems u*8..+8)
    const float* gA = A + (size_t)(m0 + (tid >> 3)) * 512 + (tid & 7) * 8;
    const int arow = tid >> 3;                         // base row
    const int apo = ((tid & 7) ^ (arow & 7)) * 8;      // phys write offset (elems)

    float4 rA[8];

#define LOADA(t) do {                                                       \
        const int _k0 = (t) * 64;                                           \
        _Pragma("unroll")                                                   \
        for (int _i = 0; _i < 4; _i++) {                                    \
            rA[2 * _i]     = *reinterpret_cast<const float4*>(gA + _k0 + (size_t)_i * 64 * 512);     \
            rA[2 * _i + 1] = *reinterpret_cast<const float4*>(gA + _k0 + (size_t)_i * 64 * 512 + 4); \
        }                                                                   \
    } while (0)

#define ISSUEW(t, bb) do {                                                  \
        const int _k0 = (t) * 64;                                           \
        _Pragma("unroll")                                                   \
        for (int _i = 0; _i < 4; _i++)                                      \
            gl16(gW + _k0 + (size_t)_i * 64 * 512,                          \
                 &Bsb[bb][wave * 512 + _i * 4096]);                         \
    } while (0)

#define WRITEA(bb) do {                                                     \
        _Pragma("unroll")                                                   \
        for (int _i = 0; _i < 4; _i++) {                                    \
            union { unsigned int u[4]; short8v v; } _pk;                    \
            _pk.u[0] = cvtpk(rA[2 * _i].x, rA[2 * _i].y);                   \
            _pk.u[1] = cvtpk(rA[2 * _i].z, rA[2 * _i].w);                   \
            _pk.u[2] = cvtpk(rA[2 * _i + 1].x, rA[2 * _i + 1].y);           \
            _pk.u[3] = cvtpk(rA[2 * _i + 1].z, rA[2 * _i + 1].w);           \
            *reinterpret_cast<short8v*>(                                    \
                &Asb[bb][(size_t)(arow + _i * 64) * 64 + apo]) = _pk.v;     \
        }                                                                   \
    } while (0)

    // ---- prologue ----
    LOADA(0);                                   // 8 ldg
    ISSUEW(0, 0);                               // 4 gl16  (12 outstanding)
    asm volatile("s_waitcnt vmcnt(4)" ::: "memory");   // A(0) done
    WRITEA(0);                                  // buf0 A-half
    LOADA(1);                                   // 8 ldg
    ISSUEW(1, 1);                               // 4 gl16  (16 outstanding)

    for (int t = 0; t < 8; ++t) {
        if (t < 7) { asm volatile("s_waitcnt vmcnt(12)" ::: "memory"); }
        else       { asm volatile("s_waitcnt vmcnt(0)" ::: "memory"); }
        asm volatile("s_waitcnt lgkmcnt(0)" ::: "memory");   // WRITEA visible
        __builtin_amdgcn_s_barrier();
        __builtin_amdgcn_sched_barrier(0);

        const int b = t & 1;
        __builtin_amdgcn_s_setprio(1);
#pragma unroll
        for (int kf = 0; kf < 2; kf++) {
            const int xofs = (kf * 32 + lg * 8);
            short8v bfr[4];
#pragma unroll
            for (int nf = 0; nf < 4; nf++) {
                const int rB = wn + nf * 16 + li;
                bfr[nf] = *reinterpret_cast<const short8v*>(
                    &Bsb[b][rB * 64 + (xofs ^ ((rB & 7) * 8))]);
            }
#pragma unroll
            for (int mf = 0; mf < 8; mf++) {
                const int rA_ = wm + mf * 16 + li;
                const short8v af = *reinterpret_cast<const short8v*>(
                    &Asb[b][rA_ * 64 + (xofs ^ ((rA_ & 7) * 8))]);
#pragma unroll
                for (int nf = 0; nf < 4; nf++)
                    acc[mf][nf] = __builtin_amdgcn_mfma_f32_16x16x32_bf16(af, bfr[nf], acc[mf][nf], 0, 0, 0);
            }
        }
        __builtin_amdgcn_s_setprio(0);

        asm volatile("s_waitcnt lgkmcnt(0)" ::: "memory");
        __builtin_amdgcn_s_barrier();
        __builtin_amdgcn_sched_barrier(0);

        if (t + 1 < 8) {
            asm volatile("s_waitcnt vmcnt(4)" ::: "memory");  // A(t+1) regs done
            WRITEA((t + 1) & 1);
            if (t + 2 < 8) {
                LOADA(t + 2);
                ISSUEW(t + 2, b);
            }
        }
    }
#undef LOADA
#undef ISSUEW
#undef WRITEA

    // epilogue: row = m0+wm+mf*16+lg*4+r, col = n0+wn+nf*16+li
#pragma unroll
    for (int nf = 0; nf < 4; nf++) {
        const int col = n0 + wn + nf * 16 + li;
        const float bb = bias[col] * bsc;
#pragma unroll
        for (int mf = 0; mf < 8; mf++) {
            const int row0 = m0 + wm + mf * 16 + lg * 4;
#pragma unroll
            for (int r = 0; r < 4; r++)
                Cout[(size_t)(row0 + r) * 512 + col] = f2bf(acc[mf][nf][r] + bb);
        }
    }
}

// ---------------------------------------------------------------------------
// bf16 GEMM, f32 output (Wo projection). m97 structure, BK=32, grid (256,4).
// At its BW floor (~31 us) — unchanged.
// ---------------------------------------------------------------------------
__global__ __launch_bounds__(256) void gemm_out(
    const unsigned short* __restrict__ A, const unsigned short* __restrict__ W,
    const float* __restrict__ bias, float* __restrict__ Cout)
{
    __shared__ __align__(16) unsigned short As[128 * 32];
    __shared__ __align__(16) unsigned short Bs[128 * 32];
    const int tid = threadIdx.x;
    const int wave = tid >> 6, lane = tid & 63;
    const int lg = lane >> 4, li = lane & 15;
    const int m0 = blockIdx.x * 128;
    const int n0 = blockIdx.y * 128;
    const int wr = (wave >> 1) * 64;
    const int wc = (wave & 1) * 64;

    f32x4 acc[4][4] = {};

    const unsigned short* ga = A + (size_t)(m0 + (tid >> 2)) * 512 + (tid & 3) * 8;
    const unsigned short* gb = W + (size_t)(n0 + (tid >> 2)) * 512 + (tid & 3) * 8;
    unsigned short* lA = &As[wave * 512];
    unsigned short* lB = &Bs[wave * 512];

    for (int k0 = 0; k0 < 512; k0 += 32) {
        __syncthreads();
        gl16(ga + k0, lA);
        gl16(ga + k0 + 64 * 512, lA + 2048);
        gl16(gb + k0, lB);
        gl16(gb + k0 + 64 * 512, lB + 2048);
        __syncthreads();

        short8v af[4], bfr[4];
#pragma unroll
        for (int i = 0; i < 4; i++) {
            af[i]  = *reinterpret_cast<const short8v*>(&As[(wr + i * 16 + li) * 32 + lg * 8]);
            bfr[i] = *reinterpret_cast<const short8v*>(&Bs[(wc + i * 16 + li) * 32 + lg * 8]);
        }
#pragma unroll
        for (int i = 0; i < 4; i++)
#pragma unroll
            for (int j = 0; j < 4; j++)
                acc[i][j] = __builtin_amdgcn_mfma_f32_16x16x32_bf16(af[i], bfr[j], acc[i][j], 0, 0, 0);
    }

#pragma unroll
    for (int j = 0; j < 4; j++) {
        const int col = n0 + wc + j * 16 + li;
        const float bb = bias[col];
#pragma unroll
        for (int i = 0; i < 4; i++) {
            const int row0 = m0 + wr + i * 16 + lg * 4;
#pragma unroll
            for (int r = 0; r < 4; r++)
                Cout[(size_t)(row0 + r) * 512 + col] = acc[i][j][r] + bb;
        }
    }
}

// ---------------------------------------------------------------------------
// bf16 flash attention v4 (round-14 verified, unchanged). QBLK=256,
// grid = (2, 512), 256 thr / 4 waves, wave owns 64 q-rows.
// ---------------------------------------------------------------------------
__global__ __launch_bounds__(256) void attn_bf16(
    const unsigned short* __restrict__ qp, const unsigned short* __restrict__ kp,
    const unsigned short* __restrict__ vp, unsigned short* __restrict__ ao)
{
    __shared__ __align__(16) unsigned short Ks[64 * 64];    // XOR-swizzled rows
    __shared__ __align__(16) unsigned short Vt[64][68];     // [d][key], pad 68
    __shared__ __align__(16) unsigned short Pl[4][16][72];  // per-wave P chunk

    const int tid = threadIdx.x;
    const int wave = tid >> 6, lane = tid & 63;
    const int lg = lane >> 4, li = lane & 15;
    const int n0 = blockIdx.x * 256;
    const int th = blockIdx.y;
    const size_t base = (size_t)(th >> 3) * EMB + (size_t)(th & 7) * HDIM;

    // ---- Q frags direct from global (one-time scatter; qb is L2/L3-warm) ----
    short8v qf[4][2];
#pragma unroll
    for (int mf = 0; mf < 4; mf++)
#pragma unroll
        for (int kf = 0; kf < 2; kf++)
            qf[mf][kf] = *reinterpret_cast<const short8v*>(
                qp + (size_t)(n0 + wave * 64 + mf * 16 + li) * ROWSTRIDE
                   + base + kf * 32 + lg * 8);

    // ---- V prefetch (tile 0): 4x4 micro-tile, 4 x global b64 ----
    const int vd0 = (tid & 15) * 4;
    const int vk0 = (tid >> 4) * 4;
    const unsigned short* gv = vp + base + vd0;
    uint2 vl[4];
#pragma unroll
    for (int i = 0; i < 4; i++)
        vl[i] = *reinterpret_cast<const uint2*>(gv + (size_t)(vk0 + i) * ROWSTRIDE);

    const short8v ones = (short8v)(short)0x3F80;   // bf16 1.0 splat
    f32x4 acc[4][4] = {};
    f32x4 acc_l[4] = {};

    for (int kv = 0; kv < 8; kv++) {
        const int k0 = kv * 64;
        __syncthreads();   // prior tile reads complete

        // stage K (XOR-swizzled source) — verified pattern
        {
            unsigned short* lk = &Ks[wave * 512];
#pragma unroll
            for (int i = 0; i < 2; i++) {
                const int r = (tid >> 3) + i * 32;
                const int srcofs = (((tid & 7) * 8) ^ ((r & 7) * 8));
                gl16(kp + (size_t)(k0 + r) * ROWSTRIDE + base + srcofs, lk + i * 2048);
            }
        }
        // stage V^T: in-reg 4x4 micro-tile transpose — verified pattern
#pragma unroll
        for (int dd = 0; dd < 4; dd++) {
            const unsigned int sel = (dd & 1) ? 0x07060302u : 0x05040100u;
            const unsigned int a = (dd < 2) ? vl[0].x : vl[0].y;
            const unsigned int b = (dd < 2) ? vl[1].x : vl[1].y;
            const unsigned int c = (dd < 2) ? vl[2].x : vl[2].y;
            const unsigned int d = (dd < 2) ? vl[3].x : vl[3].y;
            uint2 o;
            o.x = __builtin_amdgcn_perm(b, a, sel);
            o.y = __builtin_amdgcn_perm(d, c, sel);
            *reinterpret_cast<uint2*>(&Vt[vd0 + dd][vk0]) = o;
        }
        __syncthreads();   // K (vmcnt) drained, Vt visible

        // prefetch next V tile under compute
        if (kv < 7) {
#pragma unroll
            for (int i = 0; i < 4; i++)
                vl[i] = *reinterpret_cast<const uint2*>(
                    gv + (size_t)(k0 + 64 + vk0 + i) * ROWSTRIDE);
        }

        // hoist K and V frags to regs (read LDS once per iter)
        short8v kfr[4][2], vfr[4][2];
#pragma unroll
        for (int nf = 0; nf < 4; nf++) {
            const int key = nf * 16 + li;
#pragma unroll
            for (int kf = 0; kf < 2; kf++)
                kfr[nf][kf] = *reinterpret_cast<const short8v*>(
                    &Ks[key * 64 + ((kf * 32 + lg * 8) ^ ((key & 7) * 8))]);
        }
#pragma unroll
        for (int df = 0; df < 4; df++)
#pragma unroll
            for (int kf = 0; kf < 2; kf++)
                vfr[df][kf] = *reinterpret_cast<const short8v*>(
                    &Vt[df * 16 + li][kf * 32 + lg * 8]);

        // ---- per-mf: QK^T -> softmax -> P chunk -> l-sum + PV ----
#pragma unroll
        for (int mf = 0; mf < 4; mf++) {
            f32x4 s[4] = {};
#pragma unroll
            for (int nf = 0; nf < 4; nf++)
#pragma unroll
                for (int kf = 0; kf < 2; kf++)
                    s[nf] = __builtin_amdgcn_mfma_f32_16x16x32_bf16(kfr[nf][kf], qf[mf][kf], s[nf], 0, 0, 0);

#pragma unroll
            for (int nf = 0; nf < 4; nf++) {
                const float p0 = exp2f(s[nf][0]);
                const float p1 = exp2f(s[nf][1]);
                const float p2 = exp2f(s[nf][2]);
                const float p3 = exp2f(s[nf][3]);
                union { unsigned int u[2]; uint2 v; } pk2;
                pk2.u[0] = cvtpk(p0, p1);
                pk2.u[1] = cvtpk(p2, p3);
                *reinterpret_cast<uint2*>(&Pl[wave][li][nf * 16 + lg * 4]) = pk2.v;
            }

            short8v pf[2];
#pragma unroll
            for (int kf = 0; kf < 2; kf++)
                pf[kf] = *reinterpret_cast<const short8v*>(
                    &Pl[wave][li][kf * 32 + lg * 8]);
#pragma unroll
            for (int kf = 0; kf < 2; kf++)
                acc_l[mf] = __builtin_amdgcn_mfma_f32_16x16x32_bf16(pf[kf], ones, acc_l[mf], 0, 0, 0);
#pragma unroll
            for (int df = 0; df < 4; df++)
#pragma unroll
                for (int kf = 0; kf < 2; kf++)
                    acc[mf][df] = __builtin_amdgcn_mfma_f32_16x16x32_bf16(pf[kf], vfr[df][kf], acc[mf][df], 0, 0, 0);
        }
    }

    // ---- epilogue: divide by l, store bf16 ----
#pragma unroll
    for (int mf = 0; mf < 4; mf++) {
#pragma unroll
        for (int r = 0; r < 4; r++) {
            const float linv = 1.0f / acc_l[mf][r];
            const int qrow = n0 + wave * 64 + mf * 16 + lg * 4 + r;
#pragma unroll
            for (int df = 0; df < 4; df++)
                ao[(size_t)qrow * ROWSTRIDE + base + df * 16 + li] = f2bf(acc[mf][df][r] * linv);
        }
    }
}

extern "C" void kernel_launch(void* const* d_in, const int* in_sizes, int n_in,
                              void* d_out, int out_size, void* d_ws, size_t ws_size,
                              hipStream_t stream) {
    const float* values = (const float*)d_in[0];
    const float* keys   = (const float*)d_in[1];
    const float* query  = (const float*)d_in[2];
    const float* Wv = (const float*)d_in[3];
    const float* bv = (const float*)d_in[4];
    const float* Wk = (const float*)d_in[5];
    const float* bk = (const float*)d_in[6];
    const float* Wq = (const float*)d_in[7];
    const float* bq = (const float*)d_in[8];
    const float* Wo = (const float*)d_in[9];
    const float* bo = (const float*)d_in[10];
    float* out = (float*)d_out;

    unsigned short* ws16 = (unsigned short*)d_ws;
    const size_t PLANE = (size_t)MROWS * EMB;
    unsigned short* qb = ws16;                  // projected q/k/v (bf16)
    unsigned short* kb = ws16 + PLANE;
    unsigned short* vb = ws16 + 2 * PLANE;
    unsigned short* ab = ws16 + 3 * PLANE;      // attention output
    unsigned short* wb = ws16 + 4 * PLANE;      // 4 bf16 weight mats

    cvtw<<<dim3(WSEG / 4 / 256, 4), 256, 0, stream>>>(Wq, Wk, Wv, Wo, wb);

    gemm_proj3<<<dim3(MROWS / 256, EMB / 256, 3), 512, 0, stream>>>(
        query, keys, values, wb, bq, bk, bv, qb, kb, vb);

    attn_bf16<<<dim3(2, TT * NHEADS), 256, 0, stream>>>(qb, kb, vb, ab);

    gemm_out<<<dim3(MROWS / 128, EMB / 128), 256, 0, stream>>>(
        ab, wb + 3 * WSEG, bo, out);
}

// Round 19
// 220.116 us; speedup vs baseline: 1.1083x; 1.0023x over previous
//
#include <hip/hip_runtime.h>
#include <hip/hip_bf16.h>
#include <math.h>

#define NBATCH 512
#define TT 64
#define EMB 512
#define NHEADS 8
#define HDIM 64
#define MROWS (NBATCH * TT)          // 32768
#define ROWSTRIDE (TT * EMB)         // 32768 elems per batch row of a plane
#define WSEG 262144                  // 512*512 weight elems

// 1/sqrt(512) * log2(e): folded into Wq/bq so attn logits are in log2 domain
static constexpr float QSCALE = 0.0637587140f;

typedef __attribute__((ext_vector_type(8))) short short8v;  // 8 bf16 (4 VGPR)
typedef __attribute__((ext_vector_type(4))) float f32x4;

__device__ __forceinline__ unsigned short f2bf(float x) {
    union { float f; unsigned int u; } v; v.f = x;
    unsigned int r = v.u + 0x7fff + ((v.u >> 16) & 1);   // RNE
    return (unsigned short)(r >> 16);
}

// v_cvt_pk_bf16_f32: packs lo->bits[15:0], hi->bits[31:16], RNE
__device__ __forceinline__ unsigned int cvtpk(float lo, float hi) {
    unsigned int r;
    asm("v_cvt_pk_bf16_f32 %0, %1, %2" : "=v"(r) : "v"(lo), "v"(hi));
    return r;
}

__device__ __forceinline__ void gl16(const void* g, void* l) {
    __builtin_amdgcn_global_load_lds(
        (const __attribute__((address_space(1))) unsigned int*)g,
        (__attribute__((address_space(3))) unsigned int*)l, 16, 0, 0);
}

// ---------------------------------------------------------------------------
// weights fp32 -> bf16 (4 MB); seg 0 (Wq) pre-scaled by QSCALE
// ---------------------------------------------------------------------------
__global__ __launch_bounds__(256) void cvtw(
    const float* __restrict__ w0, const float* __restrict__ w1,
    const float* __restrict__ w2, const float* __restrict__ w3,
    unsigned short* __restrict__ dst)
{
    const int seg = blockIdx.y;
    const float* src = (seg == 0) ? w0 : (seg == 1) ? w1 : (seg == 2) ? w2 : w3;
    const float sc = (seg == 0) ? QSCALE : 1.0f;
    const size_t i = (size_t)blockIdx.x * 256 + threadIdx.x;   // x4 elems
    float4 v = reinterpret_cast<const float4*>(src)[i];
    ushort4 r;
    r.x = f2bf(v.x * sc); r.y = f2bf(v.y * sc); r.z = f2bf(v.z * sc); r.w = f2bf(v.w * sc);
    reinterpret_cast<ushort4*>(dst + (size_t)seg * WSEG)[i] = r;
}

// ---------------------------------------------------------------------------
// Merged q/k/v projection GEMMs (round-18 verified, unchanged): 256x256 tile,
// BK=64, deep-MFMA counted-vmcnt pipeline with fused f32->bf16 A conversion.
// ---------------------------------------------------------------------------
__global__ __launch_bounds__(512) void gemm_proj3(
    const float* __restrict__ A0, const float* __restrict__ A1,
    const float* __restrict__ A2, const unsigned short* __restrict__ Wb,
    const float* __restrict__ b0, const float* __restrict__ b1, const float* __restrict__ b2,
    unsigned short* __restrict__ o0, unsigned short* __restrict__ o1, unsigned short* __restrict__ o2)
{
    __shared__ __align__(16) unsigned short Asb[2][256 * 64];  // 2 x 32 KB
    __shared__ __align__(16) unsigned short Bsb[2][256 * 64];  // 2 x 32 KB
    const int z = blockIdx.z;
    const float* A = (z == 0) ? A0 : (z == 1) ? A1 : A2;
    const unsigned short* W = Wb + (size_t)z * WSEG;
    const float* bias = (z == 0) ? b0 : (z == 1) ? b1 : b2;
    const float bsc = (z == 0) ? QSCALE : 1.0f;
    unsigned short* Cout = (z == 0) ? o0 : (z == 1) ? o1 : o2;

    const int tid = threadIdx.x;
    const int wave = tid >> 6, lane = tid & 63;
    const int lg = lane >> 4, li = lane & 15;
    const int m0 = blockIdx.x * 256;
    const int n0 = blockIdx.y * 256;
    const int wm = (wave >> 2) * 128;       // wave row offset (0/128)
    const int wn = (wave & 3) * 64;         // wave col offset (0..192)

    f32x4 acc[8][4] = {};

    const int au = (tid & 7) ^ ((tid >> 3) & 7);
    const unsigned short* gW = W + (size_t)(n0 + (tid >> 3)) * 512 + au * 8;
    const float* gA = A + (size_t)(m0 + (tid >> 3)) * 512 + (tid & 7) * 8;
    const int arow = tid >> 3;                         // base row
    const int apo = ((tid & 7) ^ (arow & 7)) * 8;      // phys write offset (elems)

    float4 rA[8];

#define LOADA(t) do {                                                       \
        const int _k0 = (t) * 64;                                           \
        _Pragma("unroll")                                                   \
        for (int _i = 0; _i < 4; _i++) {                                    \
            rA[2 * _i]     = *reinterpret_cast<const float4*>(gA + _k0 + (size_t)_i * 64 * 512);     \
            rA[2 * _i + 1] = *reinterpret_cast<const float4*>(gA + _k0 + (size_t)_i * 64 * 512 + 4); \
        }                                                                   \
    } while (0)

#define ISSUEW(t, bb) do {                                                  \
        const int _k0 = (t) * 64;                                           \
        _Pragma("unroll")                                                   \
        for (int _i = 0; _i < 4; _i++)                                      \
            gl16(gW + _k0 + (size_t)_i * 64 * 512,                          \
                 &Bsb[bb][wave * 512 + _i * 4096]);                         \
    } while (0)

#define WRITEA(bb) do {                                                     \
        _Pragma("unroll")                                                   \
        for (int _i = 0; _i < 4; _i++) {                                    \
            union { unsigned int u[4]; short8v v; } _pk;                    \
            _pk.u[0] = cvtpk(rA[2 * _i].x, rA[2 * _i].y);                   \
            _pk.u[1] = cvtpk(rA[2 * _i].z, rA[2 * _i].w);                   \
            _pk.u[2] = cvtpk(rA[2 * _i + 1].x, rA[2 * _i + 1].y);           \
            _pk.u[3] = cvtpk(rA[2 * _i + 1].z, rA[2 * _i + 1].w);           \
            *reinterpret_cast<short8v*>(                                    \
                &Asb[bb][(size_t)(arow + _i * 64) * 64 + apo]) = _pk.v;     \
        }                                                                   \
    } while (0)

    // ---- prologue ----
    LOADA(0);
    ISSUEW(0, 0);
    asm volatile("s_waitcnt vmcnt(4)" ::: "memory");   // A(0) done
    WRITEA(0);
    LOADA(1);
    ISSUEW(1, 1);

    for (int t = 0; t < 8; ++t) {
        if (t < 7) { asm volatile("s_waitcnt vmcnt(12)" ::: "memory"); }
        else       { asm volatile("s_waitcnt vmcnt(0)" ::: "memory"); }
        asm volatile("s_waitcnt lgkmcnt(0)" ::: "memory");   // WRITEA visible
        __builtin_amdgcn_s_barrier();
        __builtin_amdgcn_sched_barrier(0);

        const int b = t & 1;
        __builtin_amdgcn_s_setprio(1);
#pragma unroll
        for (int kf = 0; kf < 2; kf++) {
            const int xofs = (kf * 32 + lg * 8);
            short8v bfr[4];
#pragma unroll
            for (int nf = 0; nf < 4; nf++) {
                const int rB = wn + nf * 16 + li;
                bfr[nf] = *reinterpret_cast<const short8v*>(
                    &Bsb[b][rB * 64 + (xofs ^ ((rB & 7) * 8))]);
            }
#pragma unroll
            for (int mf = 0; mf < 8; mf++) {
                const int rA_ = wm + mf * 16 + li;
                const short8v af = *reinterpret_cast<const short8v*>(
                    &Asb[b][rA_ * 64 + (xofs ^ ((rA_ & 7) * 8))]);
#pragma unroll
                for (int nf = 0; nf < 4; nf++)
                    acc[mf][nf] = __builtin_amdgcn_mfma_f32_16x16x32_bf16(af, bfr[nf], acc[mf][nf], 0, 0, 0);
            }
        }
        __builtin_amdgcn_s_setprio(0);

        asm volatile("s_waitcnt lgkmcnt(0)" ::: "memory");
        __builtin_amdgcn_s_barrier();
        __builtin_amdgcn_sched_barrier(0);

        if (t + 1 < 8) {
            asm volatile("s_waitcnt vmcnt(4)" ::: "memory");  // A(t+1) regs done
            WRITEA((t + 1) & 1);
            if (t + 2 < 8) {
                LOADA(t + 2);
                ISSUEW(t + 2, b);
            }
        }
    }
#undef LOADA
#undef ISSUEW
#undef WRITEA

#pragma unroll
    for (int nf = 0; nf < 4; nf++) {
        const int col = n0 + wn + nf * 16 + li;
        const float bb = bias[col] * bsc;
#pragma unroll
        for (int mf = 0; mf < 8; mf++) {
            const int row0 = m0 + wm + mf * 16 + lg * 4;
#pragma unroll
            for (int r = 0; r < 4; r++)
                Cout[(size_t)(row0 + r) * 512 + col] = f2bf(acc[mf][nf][r] + bb);
        }
    }
}

// ---------------------------------------------------------------------------
// bf16 GEMM, f32 output (Wo projection). m97 structure, BK=32, grid (256,4).
// At its BW floor (~31 us) — unchanged.
// ---------------------------------------------------------------------------
__global__ __launch_bounds__(256) void gemm_out(
    const unsigned short* __restrict__ A, const unsigned short* __restrict__ W,
    const float* __restrict__ bias, float* __restrict__ Cout)
{
    __shared__ __align__(16) unsigned short As[128 * 32];
    __shared__ __align__(16) unsigned short Bs[128 * 32];
    const int tid = threadIdx.x;
    const int wave = tid >> 6, lane = tid & 63;
    const int lg = lane >> 4, li = lane & 15;
    const int m0 = blockIdx.x * 128;
    const int n0 = blockIdx.y * 128;
    const int wr = (wave >> 1) * 64;
    const int wc = (wave & 1) * 64;

    f32x4 acc[4][4] = {};

    const unsigned short* ga = A + (size_t)(m0 + (tid >> 2)) * 512 + (tid & 3) * 8;
    const unsigned short* gb = W + (size_t)(n0 + (tid >> 2)) * 512 + (tid & 3) * 8;
    unsigned short* lA = &As[wave * 512];
    unsigned short* lB = &Bs[wave * 512];

    for (int k0 = 0; k0 < 512; k0 += 32) {
        __syncthreads();
        gl16(ga + k0, lA);
        gl16(ga + k0 + 64 * 512, lA + 2048);
        gl16(gb + k0, lB);
        gl16(gb + k0 + 64 * 512, lB + 2048);
        __syncthreads();

        short8v af[4], bfr[4];
#pragma unroll
        for (int i = 0; i < 4; i++) {
            af[i]  = *reinterpret_cast<const short8v*>(&As[(wr + i * 16 + li) * 32 + lg * 8]);
            bfr[i] = *reinterpret_cast<const short8v*>(&Bs[(wc + i * 16 + li) * 32 + lg * 8]);
        }
#pragma unroll
        for (int i = 0; i < 4; i++)
#pragma unroll
            for (int j = 0; j < 4; j++)
                acc[i][j] = __builtin_amdgcn_mfma_f32_16x16x32_bf16(af[i], bfr[j], acc[i][j], 0, 0, 0);
    }

#pragma unroll
    for (int j = 0; j < 4; j++) {
        const int col = n0 + wc + j * 16 + li;
        const float bb = bias[col];
#pragma unroll
        for (int i = 0; i < 4; i++) {
            const int row0 = m0 + wr + i * 16 + lg * 4;
#pragma unroll
            for (int r = 0; r < 4; r++)
                Cout[(size_t)(row0 + r) * 512 + col] = acc[i][j][r] + bb;
        }
    }
}

// ---------------------------------------------------------------------------
// bf16 flash attention v5: QBLK=512 (one block per (t,h) pair -> K/V read
// from HBM exactly ONCE). grid = (T*H=512), 512 thr / 8 waves; each wave
// owns 64 q-rows (identical per-wave structure/algebra to verified v4).
// Staging re-derived for 512 threads:
//   K: ONE gl16/thread (8 KB tile exactly), same XOR layout -> same reads.
//   V: 4 keys x 2 d per thread (4 x b32 load, 2 perm, 2 b64 write).
// ---------------------------------------------------------------------------
__global__ __launch_bounds__(512) void attn_bf16(
    const unsigned short* __restrict__ qp, const unsigned short* __restrict__ kp,
    const unsigned short* __restrict__ vp, unsigned short* __restrict__ ao)
{
    __shared__ __align__(16) unsigned short Ks[64 * 64];    // XOR-swizzled rows
    __shared__ __align__(16) unsigned short Vt[64][68];     // [d][key], pad 68
    __shared__ __align__(16) unsigned short Pl[8][16][72];  // per-wave P chunk

    const int tid = threadIdx.x;
    const int wave = tid >> 6, lane = tid & 63;
    const int lg = lane >> 4, li = lane & 15;
    const int th = blockIdx.x;
    const size_t base = (size_t)(th >> 3) * EMB + (size_t)(th & 7) * HDIM;

    // ---- Q frags direct from global (one-time scatter; qb is L2/L3-warm) ----
    short8v qf[4][2];
#pragma unroll
    for (int mf = 0; mf < 4; mf++)
#pragma unroll
        for (int kf = 0; kf < 2; kf++)
            qf[mf][kf] = *reinterpret_cast<const short8v*>(
                qp + (size_t)(wave * 64 + mf * 16 + li) * ROWSTRIDE
                   + base + kf * 32 + lg * 8);

    // ---- V prefetch (tile 0): 4 keys x 2 d micro-tile, 4 x b32 ----
    const int vk0 = (tid >> 5) * 4;        // key-quad (0..60)
    const int vd0 = (tid & 31) * 2;        // d-pair  (0..62)
    const unsigned short* gv = vp + base + vd0;
    unsigned int vl[4];
#pragma unroll
    for (int i = 0; i < 4; i++)
        vl[i] = *reinterpret_cast<const unsigned int*>(gv + (size_t)(vk0 + i) * ROWSTRIDE);

    const short8v ones = (short8v)(short)0x3F80;   // bf16 1.0 splat
    f32x4 acc[4][4] = {};
    f32x4 acc_l[4] = {};

    for (int kv = 0; kv < 8; kv++) {
        const int k0 = kv * 64;
        __syncthreads();   // prior tile reads complete

        // stage K (XOR-swizzled source): one gl16 per thread
        {
            const int r = tid >> 3;
            const int srcofs = (((tid & 7) * 8) ^ ((r & 7) * 8));
            gl16(kp + (size_t)(k0 + r) * ROWSTRIDE + base + srcofs, &Ks[wave * 512]);
        }
        // stage V^T: 4x2 micro-tile transpose (perm arg-order as verified v4)
#pragma unroll
        for (int dd = 0; dd < 2; dd++) {
            const unsigned int sel = (dd & 1) ? 0x07060302u : 0x05040100u;
            uint2 o;
            o.x = __builtin_amdgcn_perm(vl[1], vl[0], sel);   // [k0[dd], k1[dd]]
            o.y = __builtin_amdgcn_perm(vl[3], vl[2], sel);   // [k2[dd], k3[dd]]
            *reinterpret_cast<uint2*>(&Vt[vd0 + dd][vk0]) = o;
        }
        __syncthreads();   // K (vmcnt) drained, Vt visible

        // prefetch next V tile under compute
        if (kv < 7) {
#pragma unroll
            for (int i = 0; i < 4; i++)
                vl[i] = *reinterpret_cast<const unsigned int*>(
                    gv + (size_t)(k0 + 64 + vk0 + i) * ROWSTRIDE);
        }

        // hoist K and V frags to regs (read LDS once per iter)
        short8v kfr[4][2], vfr[4][2];
#pragma unroll
        for (int nf = 0; nf < 4; nf++) {
            const int key = nf * 16 + li;
#pragma unroll
            for (int kf = 0; kf < 2; kf++)
                kfr[nf][kf] = *reinterpret_cast<const short8v*>(
                    &Ks[key * 64 + ((kf * 32 + lg * 8) ^ ((key & 7) * 8))]);
        }
#pragma unroll
        for (int df = 0; df < 4; df++)
#pragma unroll
            for (int kf = 0; kf < 2; kf++)
                vfr[df][kf] = *reinterpret_cast<const short8v*>(
                    &Vt[df * 16 + li][kf * 32 + lg * 8]);

        // ---- per-mf: QK^T -> softmax -> P chunk -> l-sum + PV ----
#pragma unroll
        for (int mf = 0; mf < 4; mf++) {
            f32x4 s[4] = {};
#pragma unroll
            for (int nf = 0; nf < 4; nf++)
#pragma unroll
                for (int kf = 0; kf < 2; kf++)
                    s[nf] = __builtin_amdgcn_mfma_f32_16x16x32_bf16(kfr[nf][kf], qf[mf][kf], s[nf], 0, 0, 0);

#pragma unroll
            for (int nf = 0; nf < 4; nf++) {
                const float p0 = exp2f(s[nf][0]);
                const float p1 = exp2f(s[nf][1]);
                const float p2 = exp2f(s[nf][2]);
                const float p3 = exp2f(s[nf][3]);
                union { unsigned int u[2]; uint2 v; } pk2;
                pk2.u[0] = cvtpk(p0, p1);
                pk2.u[1] = cvtpk(p2, p3);
                *reinterpret_cast<uint2*>(&Pl[wave][li][nf * 16 + lg * 4]) = pk2.v;
            }

            short8v pf[2];
#pragma unroll
            for (int kf = 0; kf < 2; kf++)
                pf[kf] = *reinterpret_cast<const short8v*>(
                    &Pl[wave][li][kf * 32 + lg * 8]);
#pragma unroll
            for (int kf = 0; kf < 2; kf++)
                acc_l[mf] = __builtin_amdgcn_mfma_f32_16x16x32_bf16(pf[kf], ones, acc_l[mf], 0, 0, 0);
#pragma unroll
            for (int df = 0; df < 4; df++)
#pragma unroll
                for (int kf = 0; kf < 2; kf++)
                    acc[mf][df] = __builtin_amdgcn_mfma_f32_16x16x32_bf16(pf[kf], vfr[df][kf], acc[mf][df], 0, 0, 0);
        }
    }

    // ---- epilogue: divide by l, store bf16 ----
#pragma unroll
    for (int mf = 0; mf < 4; mf++) {
#pragma unroll
        for (int r = 0; r < 4; r++) {
            const float linv = 1.0f / acc_l[mf][r];
            const int qrow = wave * 64 + mf * 16 + lg * 4 + r;
#pragma unroll
            for (int df = 0; df < 4; df++)
                ao[(size_t)qrow * ROWSTRIDE + base + df * 16 + li] = f2bf(acc[mf][df][r] * linv);
        }
    }
}

extern "C" void kernel_launch(void* const* d_in, const int* in_sizes, int n_in,
                              void* d_out, int out_size, void* d_ws, size_t ws_size,
                              hipStream_t stream) {
    const float* values = (const float*)d_in[0];
    const float* keys   = (const float*)d_in[1];
    const float* query  = (const float*)d_in[2];
    const float* Wv = (const float*)d_in[3];
    const float* bv = (const float*)d_in[4];
    const float* Wk = (const float*)d_in[5];
    const float* bk = (const float*)d_in[6];
    const float* Wq = (const float*)d_in[7];
    const float* bq = (const float*)d_in[8];
    const float* Wo = (const float*)d_in[9];
    const float* bo = (const float*)d_in[10];
    float* out = (float*)d_out;

    unsigned short* ws16 = (unsigned short*)d_ws;
    const size_t PLANE = (size_t)MROWS * EMB;
    unsigned short* qb = ws16;                  // projected q/k/v (bf16)
    unsigned short* kb = ws16 + PLANE;
    unsigned short* vb = ws16 + 2 * PLANE;
    unsigned short* ab = ws16 + 3 * PLANE;      // attention output
    unsigned short* wb = ws16 + 4 * PLANE;      // 4 bf16 weight mats

    cvtw<<<dim3(WSEG / 4 / 256, 4), 256, 0, stream>>>(Wq, Wk, Wv, Wo, wb);

    gemm_proj3<<<dim3(MROWS / 256, EMB / 256, 3), 512, 0, stream>>>(
        query, keys, values, wb, bq, bk, bv, qb, kb, vb);

    attn_bf16<<<dim3(TT * NHEADS), 512, 0, stream>>>(qb, kb, vb, ab);

    gemm_out<<<dim3(MROWS / 128, EMB / 128), 256, 0, stream>>>(
        ab, wb + 3 * WSEG, bo, out);
}